// Round 11
// baseline (240.422 us; speedup 1.0000x reference)
//
#include <hip/hip_runtime.h>
#include <hip/hip_bf16.h>

typedef __bf16  bf16x8 __attribute__((ext_vector_type(8)));
typedef float   f32x4  __attribute__((ext_vector_type(4)));
typedef float   f32x16 __attribute__((ext_vector_type(16)));

#define EMB   1024
#define QSTR  3072                  // packed QKV row stride
#define HD    64
#define NH    16
#define SEQ   2048
#define BATCH 2
#define TOKENS (BATCH*SEQ)
#define TK    128                   // attention K-tile per barrier (2 halves)

// ---------------------------------------------------------------------------
// async global->LDS, 16 B per lane. LDS dest = wave-uniform base + lane*16.
// ---------------------------------------------------------------------------
typedef __attribute__((address_space(1))) unsigned int* gp_t;
typedef __attribute__((address_space(3))) unsigned int* lp_t;
__device__ __forceinline__ void gload16(const __bf16* g, __bf16* l) {
    __builtin_amdgcn_global_load_lds((gp_t)(unsigned long long)(const void*)g,
                                     (lp_t)(unsigned int)(unsigned long long)(void*)l,
                                     16, 0, 0);
}

// pack two f32 -> one u32 of 2 bf16
__device__ __forceinline__ unsigned int pack2(float a, float b) {
    unsigned short u0 = __builtin_bit_cast(unsigned short, (__bf16)a);
    unsigned short u1 = __builtin_bit_cast(unsigned short, (__bf16)b);
    return (unsigned int)u0 | ((unsigned int)u1 << 16);
}

// ---------------------------------------------------------------------------
// fp32 -> bf16, up to 4 sources selected by blockIdx.y, contiguous dst slabs.
// ---------------------------------------------------------------------------
__global__ __launch_bounds__(256) void cvt4_kernel(
    const float* __restrict__ s0, const float* __restrict__ s1,
    const float* __restrict__ s2, const float* __restrict__ s3,
    __bf16* __restrict__ dst, int n_per)
{
    const float* s = (blockIdx.y == 0) ? s0 : (blockIdx.y == 1) ? s1
                   : (blockIdx.y == 2) ? s2 : s3;
    int i = (blockIdx.x * 256 + threadIdx.x) * 8;
    if (i >= n_per) return;
    float4 a = *(const float4*)(s + i);
    float4 b = *(const float4*)(s + i + 4);
    __bf16 o[8] = {(__bf16)a.x, (__bf16)a.y, (__bf16)a.z, (__bf16)a.w,
                   (__bf16)b.x, (__bf16)b.y, (__bf16)b.z, (__bf16)b.w};
    *(uint4*)(dst + (size_t)blockIdx.y * n_per + i) = *(const uint4*)o;
}

// ---------------------------------------------------------------------------
// QKV GEMM: tile 128(M) x 128(N), BK=32, dbuf + global_load_lds prefetch.
// V-slab blocks (bn>=16) transpose their output tile in LDS and write
// V^T into the dead V-column region of QKVp:
//   vt_addr(bh,d,tok) = ((bh*64+d)*2 + (tok>>10))*QSTR + 2048 + (tok&1023)
// ---------------------------------------------------------------------------
__global__ __launch_bounds__(256, 3) void gemm_qkv(
    const __bf16* __restrict__ X, const __bf16* __restrict__ Wt,
    const float* __restrict__ b0, const float* __restrict__ b1,
    const float* __restrict__ b2, __bf16* __restrict__ Y)
{
    __shared__ __align__(16) __bf16 SMEM[4 * 128 * 32];   // 32 KB total
    // A dbuf at 0 / 4096; B dbuf at 8192 / 12288; epilogue T buf at 0 (18 KB)

    const int tid  = threadIdx.x;
    const int wave = tid >> 6;
    const int lane = tid & 63;
    const int quad = lane >> 4;
    const int l16  = lane & 15;
    const int warp_m = wave >> 1;
    const int warp_n = wave & 1;

    const int bm = blockIdx.y;
    const int bn = blockIdx.x;

    const int lr = lane >> 2;
    const int lc = (lane & 3) ^ ((lr >> 1) & 3);
    const __bf16* Ag = X + (size_t)(bn >> 3) * TOKENS * EMB
                         + (size_t)(bm * 128 + wave * 32 + lr) * EMB + lc * 8;
    const __bf16* Bg = Wt + (size_t)(bn * 128 + wave * 32 + lr) * EMB + lc * 8;
    const int off = wave * 1024;

    f32x4 acc[4][4] = {};

    gload16(Ag,            SMEM + off);
    gload16(Ag + 16 * EMB, SMEM + off + 512);
    gload16(Bg,            SMEM + 8192 + off);
    gload16(Bg + 16 * EMB, SMEM + 8192 + off + 512);

    for (int t = 0; t < EMB / 32; ++t) {
        const int cur = t & 1, nxt = cur ^ 1;
        __syncthreads();
        if (t + 1 < EMB / 32) {
            const __bf16* a0 = Ag + (t + 1) * 32;
            const __bf16* w0 = Bg + (t + 1) * 32;
            gload16(a0,            SMEM + nxt * 4096 + off);
            gload16(a0 + 16 * EMB, SMEM + nxt * 4096 + off + 512);
            gload16(w0,            SMEM + 8192 + nxt * 4096 + off);
            gload16(w0 + 16 * EMB, SMEM + 8192 + nxt * 4096 + off + 512);
        }

        const __bf16* Acur = SMEM + cur * 4096;
        const __bf16* Bcur = SMEM + 8192 + cur * 4096;
        bf16x8 af[4], bf[4];
        #pragma unroll
        for (int i = 0; i < 4; ++i) {
            int rowa = warp_m * 64 + i * 16 + l16;
            int rowb = warp_n * 64 + i * 16 + l16;
            af[i] = *(const bf16x8*)(Acur + (rowa * 4 + (quad ^ ((rowa >> 1) & 3))) * 8);
            bf[i] = *(const bf16x8*)(Bcur + (rowb * 4 + (quad ^ ((rowb >> 1) & 3))) * 8);
        }
        #pragma unroll
        for (int i = 0; i < 4; ++i)
            #pragma unroll
            for (int j = 0; j < 4; ++j)
                acc[i][j] = __builtin_amdgcn_mfma_f32_16x16x32_bf16(af[i], bf[j], acc[i][j], 0, 0, 0);
    }

    if (bn < 16) {
        // Q / K slabs: normal row-major write
        #pragma unroll
        for (int i = 0; i < 4; ++i)
            #pragma unroll
            for (int j = 0; j < 4; ++j) {
                int n = bn * 128 + warp_n * 64 + j * 16 + l16;
                const float* bsel = (n < 1024) ? b0 : b1;
                float bj = bsel[n & 1023];
                #pragma unroll
                for (int r = 0; r < 4; ++r) {
                    int m = bm * 128 + warp_m * 64 + i * 16 + quad * 4 + r;
                    Y[(size_t)m * QSTR + n] = (__bf16)(acc[i][j][r] + bj);
                }
            }
    } else {
        // V slab: bias + transpose (two 64-token halves through T) -> V^T map
        __bf16* T = SMEM;                     // [128][72] transpose buffer
        const int b_   = bm >> 4;
        const int tokl = (bm & 15) * 128;
        #pragma unroll
        for (int half = 0; half < 2; ++half) {
            __syncthreads();
            if (warp_m == half) {
                #pragma unroll
                for (int i = 0; i < 4; ++i)
                    #pragma unroll
                    for (int j = 0; j < 4; ++j) {
                        int nl = warp_n * 64 + j * 16 + l16;
                        float bj = b2[(bn & 7) * 128 + nl];
                        #pragma unroll
                        for (int r = 0; r < 4; ++r) {
                            int ml = i * 16 + quad * 4 + r;     // token-local 0..63
                            T[nl * 72 + ml] = (__bf16)(acc[i][j][r] + bj);
                        }
                    }
            }
            __syncthreads();
            {
                const int nl  = tid >> 1;                 // V column-local 0..127
                const int seg = tid & 1;
                const int hh  = (bn - 16) * 2 + (nl >> 6);
                const int dd  = nl & 63;
                const int tok0 = tokl + half * 64 + seg * 32;
                const int bh_ = b_ * NH + hh;
                __bf16* dst = Y + ((size_t)((bh_ * 64 + dd) * 2 + (tok0 >> 10))) * QSTR
                                + 2048 + (tok0 & 1023);
                #pragma unroll
                for (int k = 0; k < 4; ++k)
                    *(uint4*)(dst + k * 8) = *(const uint4*)&T[nl * 72 + seg * 32 + k * 8];
            }
        }
    }
}

// ---------------------------------------------------------------------------
// Final GEMM (R10-proven): tile 128x64, BK=64, dbuf + gload prefetch.
// ---------------------------------------------------------------------------
template <typename TY>
__global__ __launch_bounds__(256) void gemm_fast(
    const __bf16* __restrict__ X, const __bf16* __restrict__ Wt,
    const float* __restrict__ b0, TY* __restrict__ Y, int ldy)
{
    __shared__ __align__(16) __bf16 As[2][128 * 64];
    __shared__ __align__(16) __bf16 Bs[2][64 * 64];

    const int tid  = threadIdx.x;
    const int wave = tid >> 6;
    const int lane = tid & 63;
    const int quad = lane >> 4;
    const int l16  = lane & 15;
    const int warp_m = wave >> 1;
    const int warp_n = wave & 1;

    const int bm = blockIdx.y;
    const int bn = blockIdx.x;

    const int lr = lane >> 3;
    const int lc = (lane & 7) ^ lr;
    const __bf16* Ag = X + (size_t)(bm * 128 + wave * 32 + lr) * EMB + lc * 8;
    const __bf16* Bg = Wt + (size_t)(bn * 64 + wave * 16 + lr) * EMB + lc * 8;
    const int aoff = wave * 2048;
    const int boff = wave * 1024;

    f32x4 acc[4][2] = {};

    gload16(Ag,            As[0] + aoff);
    gload16(Ag +  8 * EMB, As[0] + aoff + 512);
    gload16(Ag + 16 * EMB, As[0] + aoff + 1024);
    gload16(Ag + 24 * EMB, As[0] + aoff + 1536);
    gload16(Bg,            Bs[0] + boff);
    gload16(Bg +  8 * EMB, Bs[0] + boff + 512);

    for (int t = 0; t < EMB / 64; ++t) {
        const int cur = t & 1, nxt = cur ^ 1;
        __syncthreads();
        if (t + 1 < EMB / 64) {
            const __bf16* a0 = Ag + (t + 1) * 64;
            const __bf16* w0 = Bg + (t + 1) * 64;
            gload16(a0,            As[nxt] + aoff);
            gload16(a0 +  8 * EMB, As[nxt] + aoff + 512);
            gload16(a0 + 16 * EMB, As[nxt] + aoff + 1024);
            gload16(a0 + 24 * EMB, As[nxt] + aoff + 1536);
            gload16(w0,            Bs[nxt] + boff);
            gload16(w0 +  8 * EMB, Bs[nxt] + boff + 512);
        }

        #pragma unroll
        for (int kk = 0; kk < 2; ++kk) {
            bf16x8 af[4], bf[2];
            #pragma unroll
            for (int i = 0; i < 4; ++i) {
                int row = warp_m * 64 + i * 16 + l16;
                af[i] = *(const bf16x8*)(As[cur] + (row * 8 + ((kk * 4 + quad) ^ (row & 7))) * 8);
            }
            #pragma unroll
            for (int j = 0; j < 2; ++j) {
                int row = warp_n * 32 + j * 16 + l16;
                bf[j] = *(const bf16x8*)(Bs[cur] + (row * 8 + ((kk * 4 + quad) ^ (row & 7))) * 8);
            }
            #pragma unroll
            for (int i = 0; i < 4; ++i)
                #pragma unroll
                for (int j = 0; j < 2; ++j)
                    acc[i][j] = __builtin_amdgcn_mfma_f32_16x16x32_bf16(af[i], bf[j], acc[i][j], 0, 0, 0);
        }
    }

    #pragma unroll
    for (int i = 0; i < 4; ++i)
        #pragma unroll
        for (int j = 0; j < 2; ++j) {
            int n = bn * 64 + warp_n * 32 + j * 16 + l16;
            float bj = b0[n];
            #pragma unroll
            for (int r = 0; r < 4; ++r) {
                int m = bm * 128 + warp_m * 64 + i * 16 + quad * 4 + r;
                Y[(size_t)m * ldy + n] = (TY)(acc[i][j][r] + bj);
            }
        }
}

// ---------------------------------------------------------------------------
// Flash attention (R10 body).  NEW: 1-D grid with bid = qt*32 + bh so all 16
// q-tile blocks of one (b,h) land on the SAME XCD (bid % 8 == bh % 8 since
// 32 % 8 == 0).  Per-XCD K/V working set drops 16 MB -> 2 MB (< 4 MB L2):
// the 512 MB/dispatch staging stream becomes L2-hits instead of hammering
// the Infinity Cache.  Also: Q pre-scaled by 0.125*log2(e) so softmax uses
// exp2f directly (saves the per-exp v_mul).
// ---------------------------------------------------------------------------
__global__ __launch_bounds__(256) void attn_kernel(
    const __bf16* __restrict__ QKV, __bf16* __restrict__ Op)
{
    __shared__ __align__(16) __bf16 Ks[2][128 * 64];   // [k-row][d]   (swz)
    __shared__ __align__(16) __bf16 Vs[2][64 * 128];   // [d-row][tok] (swz)

    const int tid  = threadIdx.x;
    const int wave = tid >> 6;
    const int lane = tid & 63;
    const int l31  = lane & 31;
    const int hi   = lane >> 5;
    const int e7   = l31 & 7;

    // bid = qt*32 + bh : same-bh blocks stride 32 apart -> same XCD (%8)
    const int bid = blockIdx.x;
    const int qt  = bid >> 5;
    const int bh  = bid & 31;            // = b*NH + h
    const int b   = bh >> 4;
    const int h   = bh & 15;

    const size_t qoff  = (size_t)b * SEQ * QSTR + (size_t)h * HD;
    const size_t obase = (size_t)b * SEQ * EMB  + (size_t)h * HD;
    const int qbase = qt * 128 + wave * 32;

    // Q fragments: lane holds Q[q=l31][d = dc*16 + 8*hi + j],
    // scaled by 0.125 * log2(e) so QK^T directly yields log2-domain scores.
    const float qscale = 0.125f * 1.44269504f;
    bf16x8 aq[4];
    {
        const __bf16* qrow = QKV + qoff + (size_t)(qbase + l31) * QSTR + hi * 8;
        #pragma unroll
        for (int dc = 0; dc < 4; ++dc) {
            bf16x8 v = *(const bf16x8*)(qrow + dc * 16);
            #pragma unroll
            for (int i = 0; i < 8; ++i) v[i] = (__bf16)((float)v[i] * qscale);
            aq[dc] = v;
        }
    }

    float  l4[4] = {};
    f32x16 oaccA[2] = {};
    f32x16 oaccB[2] = {};

    // ---- staging geometry (pre-swizzled source, linear LDS dest) ----
    const int kr = tid >> 3;
    const int kc = ((tid & 7) ^ (kr & 7)) << 3;
    const __bf16* Kg0 = QKV + qoff + EMB + (size_t)kr * QSTR + kc;
    const int vr  = tid >> 4;
    const int vpc = tid & 15;
    const int vlc = (vpc & 8) | ((vpc ^ vr) & 7);        // logical chunk (low3 XOR)
    const __bf16* Vg0 = QKV + ((size_t)(bh * 64 + vr) * 2) * QSTR + 2048 + vlc * 8;

    #define STAGE(buf, kb)                                                        \
        {                                                                         \
            _Pragma("unroll")                                                     \
            for (int i_ = 0; i_ < 4; ++i_)                                        \
                gload16(Kg0 + (size_t)((kb) + i_ * 32) * QSTR,                    \
                        Ks[buf] + i_ * 2048 + tid * 8);                           \
            const size_t vt_ = (size_t)((kb) >> 10) * QSTR + ((kb) & 1023);       \
            _Pragma("unroll")                                                     \
            for (int i_ = 0; i_ < 4; ++i_)                                        \
                gload16(Vg0 + (size_t)i_ * 32 * QSTR + vt_,                       \
                        Vs[buf] + i_ * 2048 + tid * 8);                           \
        }

    // softmax of one 64-k half: s (log2-domain) -> paf (PV A-frags) + l partials
    #define SOFTMAX(sreg, paf)                                                    \
        {                                                                         \
            unsigned int pw[2][4][2];                                             \
            _Pragma("unroll")                                                     \
            for (int kt = 0; kt < 2; ++kt)                                        \
                _Pragma("unroll")                                                 \
                for (int bq = 0; bq < 4; ++bq) {                                  \
                    float e0 = __builtin_exp2f(sreg[kt][bq * 4 + 0]);             \
                    float e1 = __builtin_exp2f(sreg[kt][bq * 4 + 1]);             \
                    float e2 = __builtin_exp2f(sreg[kt][bq * 4 + 2]);             \
                    float e3 = __builtin_exp2f(sreg[kt][bq * 4 + 3]);             \
                    l4[(kt * 4 + bq) & 3] += (e0 + e1) + (e2 + e3);               \
                    pw[kt][bq][0] = pack2(e0, e1);                                \
                    pw[kt][bq][1] = pack2(e2, e3);                                \
                }                                                                 \
            _Pragma("unroll")                                                     \
            for (int kt = 0; kt < 2; ++kt)                                        \
                _Pragma("unroll")                                                 \
                for (int m = 0; m < 2; ++m) {                                     \
                    unsigned x0 = pw[kt][2 * m][0],     x1 = pw[kt][2 * m][1];    \
                    unsigned y0 = pw[kt][2 * m + 1][0], y1 = pw[kt][2 * m + 1][1];\
                    unsigned px0 = __shfl_xor(x0, 32, 64);                        \
                    unsigned px1 = __shfl_xor(x1, 32, 64);                        \
                    unsigned py0 = __shfl_xor(y0, 32, 64);                        \
                    unsigned py1 = __shfl_xor(y1, 32, 64);                        \
                    uint4 fw;                                                     \
                    fw.x = hi ? py0 : x0;                                         \
                    fw.y = hi ? py1 : x1;                                         \
                    fw.z = hi ? y0  : px0;                                        \
                    fw.w = hi ? y1  : px1;                                        \
                    paf[kt * 2 + m] = __builtin_bit_cast(bf16x8, fw);             \
                }                                                                 \
        }

    STAGE(0, 0);

    for (int t = 0; t < SEQ / TK; ++t) {
        const int cur = t & 1, nxt = cur ^ 1;
        __syncthreads();                 // vmcnt drained -> buf[cur] ready
        if (t + 1 < SEQ / TK) STAGE(nxt, (t + 1) * TK);

        const __bf16* K0 = Ks[cur];             // rows 0..63
        const __bf16* K1 = Ks[cur] + 4096;      // rows 64..127
        const __bf16* Vc = Vs[cur];

        // ---- QKT half0 ----
        f32x16 sA[2] = {};
        #pragma unroll
        for (int kt = 0; kt < 2; ++kt)
            #pragma unroll
            for (int dc = 0; dc < 4; ++dc) {
                bf16x8 kf = *(const bf16x8*)(K0 + (kt * 32 + l31) * 64
                                             + (((2 * dc + hi) ^ e7) << 3));
                sA[kt] = __builtin_amdgcn_mfma_f32_32x32x16_bf16(kf, aq[dc], sA[kt], 0, 0, 0);
            }

        // ---- softmax half0 ----
        bf16x8 pafA[4];
        SOFTMAX(sA, pafA)

        // ---- QKT half1 (independent of pafA) ----
        f32x16 sB[2] = {};
        #pragma unroll
        for (int kt = 0; kt < 2; ++kt)
            #pragma unroll
            for (int dc = 0; dc < 4; ++dc) {
                bf16x8 kf = *(const bf16x8*)(K1 + (kt * 32 + l31) * 64
                                             + (((2 * dc + hi) ^ e7) << 3));
                sB[kt] = __builtin_amdgcn_mfma_f32_32x32x16_bf16(kf, aq[dc], sB[kt], 0, 0, 0);
            }

        // ---- PV half0 (interleaves with softmax half1 below) ----
        #pragma unroll
        for (int dh = 0; dh < 2; ++dh)
            #pragma unroll
            for (int ks = 0; ks < 4; ++ks) {
                bf16x8 bvf = *(const bf16x8*)(Vc + (dh * 32 + l31) * 128
                                              + ((0 + ((2 * ks + hi) ^ e7)) << 3));
                oaccA[dh] = __builtin_amdgcn_mfma_f32_32x32x16_bf16(pafA[ks], bvf, oaccA[dh], 0, 0, 0);
            }

        // ---- softmax half1 ----
        bf16x8 pafB[4];
        SOFTMAX(sB, pafB)

        // ---- PV half1 (independent accumulator) ----
        #pragma unroll
        for (int dh = 0; dh < 2; ++dh)
            #pragma unroll
            for (int ks = 0; ks < 4; ++ks) {
                bf16x8 bvf = *(const bf16x8*)(Vc + (dh * 32 + l31) * 128
                                              + ((8 + ((2 * ks + hi) ^ e7)) << 3));
                oaccB[dh] = __builtin_amdgcn_mfma_f32_32x32x16_bf16(pafB[ks], bvf, oaccB[dh], 0, 0, 0);
            }
    }

    // combine split accumulators
    f32x16 oacc[2];
    oacc[0] = oaccA[0] + oaccB[0];
    oacc[1] = oaccA[1] + oaccB[1];
    float l_run = (l4[0] + l4[1]) + (l4[2] + l4[3]);

    // lanes l and l+32 hold complementary k-halves for the same q = l31
    float lf = l_run + __shfl_xor(l_run, 32, 64);

    #pragma unroll
    for (int r = 0; r < 16; ++r) {
        int qr = (r & 3) + 8 * (r >> 2) + 4 * hi;    // O row (q) for this reg
        float lq = __shfl(lf, qr, 64);               // lane qr (0..31) holds l[qr]
        #pragma unroll
        for (int dh = 0; dh < 2; ++dh)
            Op[obase + (size_t)(qbase + qr) * EMB + dh * 32 + l31] =
                (__bf16)(oacc[dh][r] / lq);
    }
    #undef STAGE
    #undef SOFTMAX
}

// ---------------------------------------------------------------------------
extern "C" void kernel_launch(void* const* d_in, const int* in_sizes, int n_in,
                              void* d_out, int out_size, void* d_ws, size_t ws_size,
                              hipStream_t stream) {
    const float* Qin = (const float*)d_in[0];
    const float* Kin = (const float*)d_in[1];
    const float* Vin = (const float*)d_in[2];
    const float* Wq  = (const float*)d_in[3];
    const float* bq  = (const float*)d_in[4];
    const float* Wk  = (const float*)d_in[5];
    const float* bk  = (const float*)d_in[6];
    const float* Wv  = (const float*)d_in[7];
    const float* bv  = (const float*)d_in[8];
    const float* Wo  = (const float*)d_in[9];
    const float* bo  = (const float*)d_in[10];

    const size_t TENS = (size_t)TOKENS * EMB;    // 4,194,304 elems
    const size_t WEL  = (size_t)EMB * EMB;       // 1,048,576 elems
    __bf16* ws = (__bf16*)d_ws;
    __bf16* Xin  = ws;                           // [3][4096][1024]
    __bf16* Wb   = ws + 3 * TENS;                // [4][1024][1024]
    __bf16* QKVp = ws + 3 * TENS + 4 * WEL;      // [4096][3072] (V cols hold V^T map)
    __bf16* Ap   = ws;                           // reuses Xin slab 0 (attn out)

    cvt4_kernel<<<dim3((unsigned)(TENS / 2048), 3), 256, 0, stream>>>(
        Qin, Kin, Vin, Vin, Xin, (int)TENS);
    cvt4_kernel<<<dim3((unsigned)(WEL / 2048), 4), 256, 0, stream>>>(
        Wq, Wk, Wv, Wo, Wb, (int)WEL);

    // merged QKV projection (V^T fused into epilogue): grid (24,32)=768
    gemm_qkv<<<dim3(QSTR / 128, TOKENS / 128), 256, 0, stream>>>(
        Xin, Wb, bq, bk, bv, QKVp);

    // 1-D grid, bid = qt*32 + bh -> same-(b,h) blocks share an XCD (L2 reuse)
    attn_kernel<<<dim3(16 * 32), 256, 0, stream>>>(QKVp, Ap);

    // output projection: 128x64 tiles, grid (16,32)=512
    gemm_fast<float><<<dim3(EMB / 64, TOKENS / 128), 256, 0, stream>>>(
        Ap, Wb + 3 * WEL, bo, (float*)d_out, EMB);
}

// Round 12
// 225.708 us; speedup vs baseline: 1.0652x; 1.0652x over previous
//
#include <hip/hip_runtime.h>
#include <hip/hip_bf16.h>

typedef __bf16  bf16x8 __attribute__((ext_vector_type(8)));
typedef float   f32x4  __attribute__((ext_vector_type(4)));
typedef float   f32x16 __attribute__((ext_vector_type(16)));

#define EMB   1024
#define QSTR  3072                  // packed QKV row stride
#define HD    64
#define NH    16
#define SEQ   2048
#define BATCH 2
#define TOKENS (BATCH*SEQ)
#define TK    128                   // attention K-tile per barrier (2 halves)

// native 2^x (v_exp_f32). Host pass sees fallback; device pass gets builtin.
#if __has_builtin(__builtin_amdgcn_exp2f)
#define EXP2(x) __builtin_amdgcn_exp2f(x)
#else
#define EXP2(x) __expf((x) * 0.69314718f)
#endif

// ---------------------------------------------------------------------------
// async global->LDS, 16 B per lane. LDS dest = wave-uniform base + lane*16.
// ---------------------------------------------------------------------------
typedef __attribute__((address_space(1))) unsigned int* gp_t;
typedef __attribute__((address_space(3))) unsigned int* lp_t;
__device__ __forceinline__ void gload16(const __bf16* g, __bf16* l) {
    __builtin_amdgcn_global_load_lds((gp_t)(unsigned long long)(const void*)g,
                                     (lp_t)(unsigned int)(unsigned long long)(void*)l,
                                     16, 0, 0);
}

// pack two f32 -> one u32 of 2 bf16
__device__ __forceinline__ unsigned int pack2(float a, float b) {
    unsigned short u0 = __builtin_bit_cast(unsigned short, (__bf16)a);
    unsigned short u1 = __builtin_bit_cast(unsigned short, (__bf16)b);
    return (unsigned int)u0 | ((unsigned int)u1 << 16);
}

// ---------------------------------------------------------------------------
// fp32 -> bf16, up to 4 sources selected by blockIdx.y, contiguous dst slabs.
// ---------------------------------------------------------------------------
__global__ __launch_bounds__(256) void cvt4_kernel(
    const float* __restrict__ s0, const float* __restrict__ s1,
    const float* __restrict__ s2, const float* __restrict__ s3,
    __bf16* __restrict__ dst, int n_per)
{
    const float* s = (blockIdx.y == 0) ? s0 : (blockIdx.y == 1) ? s1
                   : (blockIdx.y == 2) ? s2 : s3;
    int i = (blockIdx.x * 256 + threadIdx.x) * 8;
    if (i >= n_per) return;
    float4 a = *(const float4*)(s + i);
    float4 b = *(const float4*)(s + i + 4);
    __bf16 o[8] = {(__bf16)a.x, (__bf16)a.y, (__bf16)a.z, (__bf16)a.w,
                   (__bf16)b.x, (__bf16)b.y, (__bf16)b.z, (__bf16)b.w};
    *(uint4*)(dst + (size_t)blockIdx.y * n_per + i) = *(const uint4*)o;
}

// ---------------------------------------------------------------------------
// QKV GEMM: tile 128(M) x 128(N), BK=32, dbuf + global_load_lds prefetch.
// V-slab blocks (bn>=16) transpose their output tile in LDS and write
// V^T into the dead V-column region of QKVp:
//   vt_addr(bh,d,tok) = ((bh*64+d)*2 + (tok>>10))*QSTR + 2048 + (tok&1023)
// ---------------------------------------------------------------------------
__global__ __launch_bounds__(256, 3) void gemm_qkv(
    const __bf16* __restrict__ X, const __bf16* __restrict__ Wt,
    const float* __restrict__ b0, const float* __restrict__ b1,
    const float* __restrict__ b2, __bf16* __restrict__ Y)
{
    __shared__ __align__(16) __bf16 SMEM[4 * 128 * 32];   // 32 KB total
    // A dbuf at 0 / 4096; B dbuf at 8192 / 12288; epilogue T buf at 0 (18 KB)

    const int tid  = threadIdx.x;
    const int wave = tid >> 6;
    const int lane = tid & 63;
    const int quad = lane >> 4;
    const int l16  = lane & 15;
    const int warp_m = wave >> 1;
    const int warp_n = wave & 1;

    const int bm = blockIdx.y;
    const int bn = blockIdx.x;

    const int lr = lane >> 2;
    const int lc = (lane & 3) ^ ((lr >> 1) & 3);
    const __bf16* Ag = X + (size_t)(bn >> 3) * TOKENS * EMB
                         + (size_t)(bm * 128 + wave * 32 + lr) * EMB + lc * 8;
    const __bf16* Bg = Wt + (size_t)(bn * 128 + wave * 32 + lr) * EMB + lc * 8;
    const int off = wave * 1024;

    f32x4 acc[4][4] = {};

    gload16(Ag,            SMEM + off);
    gload16(Ag + 16 * EMB, SMEM + off + 512);
    gload16(Bg,            SMEM + 8192 + off);
    gload16(Bg + 16 * EMB, SMEM + 8192 + off + 512);

    for (int t = 0; t < EMB / 32; ++t) {
        const int cur = t & 1, nxt = cur ^ 1;
        __syncthreads();
        if (t + 1 < EMB / 32) {
            const __bf16* a0 = Ag + (t + 1) * 32;
            const __bf16* w0 = Bg + (t + 1) * 32;
            gload16(a0,            SMEM + nxt * 4096 + off);
            gload16(a0 + 16 * EMB, SMEM + nxt * 4096 + off + 512);
            gload16(w0,            SMEM + 8192 + nxt * 4096 + off);
            gload16(w0 + 16 * EMB, SMEM + 8192 + nxt * 4096 + off + 512);
        }

        const __bf16* Acur = SMEM + cur * 4096;
        const __bf16* Bcur = SMEM + 8192 + cur * 4096;
        bf16x8 af[4], bf[4];
        #pragma unroll
        for (int i = 0; i < 4; ++i) {
            int rowa = warp_m * 64 + i * 16 + l16;
            int rowb = warp_n * 64 + i * 16 + l16;
            af[i] = *(const bf16x8*)(Acur + (rowa * 4 + (quad ^ ((rowa >> 1) & 3))) * 8);
            bf[i] = *(const bf16x8*)(Bcur + (rowb * 4 + (quad ^ ((rowb >> 1) & 3))) * 8);
        }
        #pragma unroll
        for (int i = 0; i < 4; ++i)
            #pragma unroll
            for (int j = 0; j < 4; ++j)
                acc[i][j] = __builtin_amdgcn_mfma_f32_16x16x32_bf16(af[i], bf[j], acc[i][j], 0, 0, 0);
    }

    if (bn < 16) {
        // Q / K slabs: normal row-major write
        #pragma unroll
        for (int i = 0; i < 4; ++i)
            #pragma unroll
            for (int j = 0; j < 4; ++j) {
                int n = bn * 128 + warp_n * 64 + j * 16 + l16;
                const float* bsel = (n < 1024) ? b0 : b1;
                float bj = bsel[n & 1023];
                #pragma unroll
                for (int r = 0; r < 4; ++r) {
                    int m = bm * 128 + warp_m * 64 + i * 16 + quad * 4 + r;
                    Y[(size_t)m * QSTR + n] = (__bf16)(acc[i][j][r] + bj);
                }
            }
    } else {
        // V slab: bias + transpose (two 64-token halves through T) -> V^T map
        __bf16* T = SMEM;                     // [128][72] transpose buffer
        const int b_   = bm >> 4;
        const int tokl = (bm & 15) * 128;
        #pragma unroll
        for (int half = 0; half < 2; ++half) {
            __syncthreads();
            if (warp_m == half) {
                #pragma unroll
                for (int i = 0; i < 4; ++i)
                    #pragma unroll
                    for (int j = 0; j < 4; ++j) {
                        int nl = warp_n * 64 + j * 16 + l16;
                        float bj = b2[(bn & 7) * 128 + nl];
                        #pragma unroll
                        for (int r = 0; r < 4; ++r) {
                            int ml = i * 16 + quad * 4 + r;     // token-local 0..63
                            T[nl * 72 + ml] = (__bf16)(acc[i][j][r] + bj);
                        }
                    }
            }
            __syncthreads();
            {
                const int nl  = tid >> 1;                 // V column-local 0..127
                const int seg = tid & 1;
                const int hh  = (bn - 16) * 2 + (nl >> 6);
                const int dd  = nl & 63;
                const int tok0 = tokl + half * 64 + seg * 32;
                const int bh_ = b_ * NH + hh;
                __bf16* dst = Y + ((size_t)((bh_ * 64 + dd) * 2 + (tok0 >> 10))) * QSTR
                                + 2048 + (tok0 & 1023);
                #pragma unroll
                for (int k = 0; k < 4; ++k)
                    *(uint4*)(dst + k * 8) = *(const uint4*)&T[nl * 72 + seg * 32 + k * 8];
            }
        }
    }
}

// ---------------------------------------------------------------------------
// Final GEMM (R10-proven): tile 128x64, BK=64, dbuf + gload prefetch.
// ---------------------------------------------------------------------------
template <typename TY>
__global__ __launch_bounds__(256) void gemm_fast(
    const __bf16* __restrict__ X, const __bf16* __restrict__ Wt,
    const float* __restrict__ b0, TY* __restrict__ Y, int ldy)
{
    __shared__ __align__(16) __bf16 As[2][128 * 64];
    __shared__ __align__(16) __bf16 Bs[2][64 * 64];

    const int tid  = threadIdx.x;
    const int wave = tid >> 6;
    const int lane = tid & 63;
    const int quad = lane >> 4;
    const int l16  = lane & 15;
    const int warp_m = wave >> 1;
    const int warp_n = wave & 1;

    const int bm = blockIdx.y;
    const int bn = blockIdx.x;

    const int lr = lane >> 3;
    const int lc = (lane & 7) ^ lr;
    const __bf16* Ag = X + (size_t)(bm * 128 + wave * 32 + lr) * EMB + lc * 8;
    const __bf16* Bg = Wt + (size_t)(bn * 64 + wave * 16 + lr) * EMB + lc * 8;
    const int aoff = wave * 2048;
    const int boff = wave * 1024;

    f32x4 acc[4][2] = {};

    gload16(Ag,            As[0] + aoff);
    gload16(Ag +  8 * EMB, As[0] + aoff + 512);
    gload16(Ag + 16 * EMB, As[0] + aoff + 1024);
    gload16(Ag + 24 * EMB, As[0] + aoff + 1536);
    gload16(Bg,            Bs[0] + boff);
    gload16(Bg +  8 * EMB, Bs[0] + boff + 512);

    for (int t = 0; t < EMB / 64; ++t) {
        const int cur = t & 1, nxt = cur ^ 1;
        __syncthreads();
        if (t + 1 < EMB / 64) {
            const __bf16* a0 = Ag + (t + 1) * 64;
            const __bf16* w0 = Bg + (t + 1) * 64;
            gload16(a0,            As[nxt] + aoff);
            gload16(a0 +  8 * EMB, As[nxt] + aoff + 512);
            gload16(a0 + 16 * EMB, As[nxt] + aoff + 1024);
            gload16(a0 + 24 * EMB, As[nxt] + aoff + 1536);
            gload16(w0,            Bs[nxt] + boff);
            gload16(w0 +  8 * EMB, Bs[nxt] + boff + 512);
        }

        #pragma unroll
        for (int kk = 0; kk < 2; ++kk) {
            bf16x8 af[4], bf[2];
            #pragma unroll
            for (int i = 0; i < 4; ++i) {
                int row = warp_m * 64 + i * 16 + l16;
                af[i] = *(const bf16x8*)(As[cur] + (row * 8 + ((kk * 4 + quad) ^ (row & 7))) * 8);
            }
            #pragma unroll
            for (int j = 0; j < 2; ++j) {
                int row = warp_n * 32 + j * 16 + l16;
                bf[j] = *(const bf16x8*)(Bs[cur] + (row * 8 + ((kk * 4 + quad) ^ (row & 7))) * 8);
            }
            #pragma unroll
            for (int i = 0; i < 4; ++i)
                #pragma unroll
                for (int j = 0; j < 2; ++j)
                    acc[i][j] = __builtin_amdgcn_mfma_f32_16x16x32_bf16(af[i], bf[j], acc[i][j], 0, 0, 0);
        }
    }

    #pragma unroll
    for (int i = 0; i < 4; ++i)
        #pragma unroll
        for (int j = 0; j < 2; ++j) {
            int n = bn * 64 + warp_n * 32 + j * 16 + l16;
            float bj = b0[n];
            #pragma unroll
            for (int r = 0; r < 4; ++r) {
                int m = bm * 128 + warp_m * 64 + i * 16 + quad * 4 + r;
                Y[(size_t)m * ldy + n] = (TY)(acc[i][j][r] + bj);
            }
        }
}

// ---------------------------------------------------------------------------
// Flash attention (R10 body + fixes).
// Grid: 1-D, bid = qt*32 + ((bh + (qt&8)) & 31).
//  - XCD locality kept: bid%8 == bh%8 (offset is a multiple of 8), so all 16
//    q-tile blocks of one (b,h) share an XCD -> K/V staging is L2-resident
//    (R11 measured FETCH 70 MB -> 12.4 MB).
//  - De-twinned: co-resident pair (bid, bid+256) decodes to bh and bh+-8 —
//    different streams, uncorrelated barrier phases (R11's twins were
//    lockstep-identical, worst-case co-scheduling).
// Softmax: native v_exp_f32 via __builtin_amdgcn_exp2f on log2-domain
// scores (Q pre-scaled by 0.125*log2e). R11's __builtin_exp2f hit the
// precise OCML path (+13 us VALU) — root cause of the regression.
// ---------------------------------------------------------------------------
__global__ __launch_bounds__(256) void attn_kernel(
    const __bf16* __restrict__ QKV, __bf16* __restrict__ Op)
{
    __shared__ __align__(16) __bf16 Ks[2][128 * 64];   // [k-row][d]   (swz)
    __shared__ __align__(16) __bf16 Vs[2][64 * 128];   // [d-row][tok] (swz)

    const int tid  = threadIdx.x;
    const int wave = tid >> 6;
    const int lane = tid & 63;
    const int l31  = lane & 31;
    const int hi   = lane >> 5;
    const int e7   = l31 & 7;

    // decode de-twinned XCD-local mapping
    const int bid = blockIdx.x;
    const int qt  = bid >> 5;
    const int bh  = ((bid & 31) - (qt & 8)) & 31;   // = b*NH + h
    const int b   = bh >> 4;
    const int h   = bh & 15;

    const size_t qoff  = (size_t)b * SEQ * QSTR + (size_t)h * HD;
    const size_t obase = (size_t)b * SEQ * EMB  + (size_t)h * HD;
    const int qbase = qt * 128 + wave * 32;

    // Q fragments: lane holds Q[q=l31][d = dc*16 + 8*hi + j],
    // scaled by 0.125 * log2(e) so QK^T directly yields log2-domain scores.
    const float qscale = 0.125f * 1.44269504f;
    bf16x8 aq[4];
    {
        const __bf16* qrow = QKV + qoff + (size_t)(qbase + l31) * QSTR + hi * 8;
        #pragma unroll
        for (int dc = 0; dc < 4; ++dc) {
            bf16x8 v = *(const bf16x8*)(qrow + dc * 16);
            #pragma unroll
            for (int i = 0; i < 8; ++i) v[i] = (__bf16)((float)v[i] * qscale);
            aq[dc] = v;
        }
    }

    float  l4[4] = {};
    f32x16 oaccA[2] = {};
    f32x16 oaccB[2] = {};

    // ---- staging geometry (pre-swizzled source, linear LDS dest) ----
    const int kr = tid >> 3;
    const int kc = ((tid & 7) ^ (kr & 7)) << 3;
    const __bf16* Kg0 = QKV + qoff + EMB + (size_t)kr * QSTR + kc;
    const int vr  = tid >> 4;
    const int vpc = tid & 15;
    const int vlc = (vpc & 8) | ((vpc ^ vr) & 7);        // logical chunk (low3 XOR)
    const __bf16* Vg0 = QKV + ((size_t)(bh * 64 + vr) * 2) * QSTR + 2048 + vlc * 8;

    #define STAGE(buf, kb)                                                        \
        {                                                                         \
            _Pragma("unroll")                                                     \
            for (int i_ = 0; i_ < 4; ++i_)                                        \
                gload16(Kg0 + (size_t)((kb) + i_ * 32) * QSTR,                    \
                        Ks[buf] + i_ * 2048 + tid * 8);                           \
            const size_t vt_ = (size_t)((kb) >> 10) * QSTR + ((kb) & 1023);       \
            _Pragma("unroll")                                                     \
            for (int i_ = 0; i_ < 4; ++i_)                                        \
                gload16(Vg0 + (size_t)i_ * 32 * QSTR + vt_,                       \
                        Vs[buf] + i_ * 2048 + tid * 8);                           \
        }

    // softmax of one 64-k half: s (log2-domain) -> paf (PV A-frags) + l partials
    #define SOFTMAX(sreg, paf)                                                    \
        {                                                                         \
            unsigned int pw[2][4][2];                                             \
            _Pragma("unroll")                                                     \
            for (int kt = 0; kt < 2; ++kt)                                        \
                _Pragma("unroll")                                                 \
                for (int bq = 0; bq < 4; ++bq) {                                  \
                    float e0 = EXP2(sreg[kt][bq * 4 + 0]);                        \
                    float e1 = EXP2(sreg[kt][bq * 4 + 1]);                        \
                    float e2 = EXP2(sreg[kt][bq * 4 + 2]);                        \
                    float e3 = EXP2(sreg[kt][bq * 4 + 3]);                        \
                    l4[(kt * 4 + bq) & 3] += (e0 + e1) + (e2 + e3);               \
                    pw[kt][bq][0] = pack2(e0, e1);                                \
                    pw[kt][bq][1] = pack2(e2, e3);                                \
                }                                                                 \
            _Pragma("unroll")                                                     \
            for (int kt = 0; kt < 2; ++kt)                                        \
                _Pragma("unroll")                                                 \
                for (int m = 0; m < 2; ++m) {                                     \
                    unsigned x0 = pw[kt][2 * m][0],     x1 = pw[kt][2 * m][1];    \
                    unsigned y0 = pw[kt][2 * m + 1][0], y1 = pw[kt][2 * m + 1][1];\
                    unsigned px0 = __shfl_xor(x0, 32, 64);                        \
                    unsigned px1 = __shfl_xor(x1, 32, 64);                        \
                    unsigned py0 = __shfl_xor(y0, 32, 64);                        \
                    unsigned py1 = __shfl_xor(y1, 32, 64);                        \
                    uint4 fw;                                                     \
                    fw.x = hi ? py0 : x0;                                         \
                    fw.y = hi ? py1 : x1;                                         \
                    fw.z = hi ? y0  : px0;                                        \
                    fw.w = hi ? y1  : px1;                                        \
                    paf[kt * 2 + m] = __builtin_bit_cast(bf16x8, fw);             \
                }                                                                 \
        }

    STAGE(0, 0);

    for (int t = 0; t < SEQ / TK; ++t) {
        const int cur = t & 1, nxt = cur ^ 1;
        __syncthreads();                 // vmcnt drained -> buf[cur] ready
        if (t + 1 < SEQ / TK) STAGE(nxt, (t + 1) * TK);

        const __bf16* K0 = Ks[cur];             // rows 0..63
        const __bf16* K1 = Ks[cur] + 4096;      // rows 64..127
        const __bf16* Vc = Vs[cur];

        // ---- QKT half0 ----
        f32x16 sA[2] = {};
        #pragma unroll
        for (int kt = 0; kt < 2; ++kt)
            #pragma unroll
            for (int dc = 0; dc < 4; ++dc) {
                bf16x8 kf = *(const bf16x8*)(K0 + (kt * 32 + l31) * 64
                                             + (((2 * dc + hi) ^ e7) << 3));
                sA[kt] = __builtin_amdgcn_mfma_f32_32x32x16_bf16(kf, aq[dc], sA[kt], 0, 0, 0);
            }

        // ---- softmax half0 ----
        bf16x8 pafA[4];
        SOFTMAX(sA, pafA)

        // ---- QKT half1 (independent of pafA) ----
        f32x16 sB[2] = {};
        #pragma unroll
        for (int kt = 0; kt < 2; ++kt)
            #pragma unroll
            for (int dc = 0; dc < 4; ++dc) {
                bf16x8 kf = *(const bf16x8*)(K1 + (kt * 32 + l31) * 64
                                             + (((2 * dc + hi) ^ e7) << 3));
                sB[kt] = __builtin_amdgcn_mfma_f32_32x32x16_bf16(kf, aq[dc], sB[kt], 0, 0, 0);
            }

        // ---- PV half0 (interleaves with softmax half1 below) ----
        #pragma unroll
        for (int dh = 0; dh < 2; ++dh)
            #pragma unroll
            for (int ks = 0; ks < 4; ++ks) {
                bf16x8 bvf = *(const bf16x8*)(Vc + (dh * 32 + l31) * 128
                                              + ((0 + ((2 * ks + hi) ^ e7)) << 3));
                oaccA[dh] = __builtin_amdgcn_mfma_f32_32x32x16_bf16(pafA[ks], bvf, oaccA[dh], 0, 0, 0);
            }

        // ---- softmax half1 ----
        bf16x8 pafB[4];
        SOFTMAX(sB, pafB)

        // ---- PV half1 (independent accumulator) ----
        #pragma unroll
        for (int dh = 0; dh < 2; ++dh)
            #pragma unroll
            for (int ks = 0; ks < 4; ++ks) {
                bf16x8 bvf = *(const bf16x8*)(Vc + (dh * 32 + l31) * 128
                                              + ((8 + ((2 * ks + hi) ^ e7)) << 3));
                oaccB[dh] = __builtin_amdgcn_mfma_f32_32x32x16_bf16(pafB[ks], bvf, oaccB[dh], 0, 0, 0);
            }
    }

    // combine split accumulators
    f32x16 oacc[2];
    oacc[0] = oaccA[0] + oaccB[0];
    oacc[1] = oaccA[1] + oaccB[1];
    float l_run = (l4[0] + l4[1]) + (l4[2] + l4[3]);

    // lanes l and l+32 hold complementary k-halves for the same q = l31
    float lf = l_run + __shfl_xor(l_run, 32, 64);

    #pragma unroll
    for (int r = 0; r < 16; ++r) {
        int qr = (r & 3) + 8 * (r >> 2) + 4 * hi;    // O row (q) for this reg
        float lq = __shfl(lf, qr, 64);               // lane qr (0..31) holds l[qr]
        #pragma unroll
        for (int dh = 0; dh < 2; ++dh)
            Op[obase + (size_t)(qbase + qr) * EMB + dh * 32 + l31] =
                (__bf16)(oacc[dh][r] / lq);
    }
    #undef STAGE
    #undef SOFTMAX
}

// ---------------------------------------------------------------------------
extern "C" void kernel_launch(void* const* d_in, const int* in_sizes, int n_in,
                              void* d_out, int out_size, void* d_ws, size_t ws_size,
                              hipStream_t stream) {
    const float* Qin = (const float*)d_in[0];
    const float* Kin = (const float*)d_in[1];
    const float* Vin = (const float*)d_in[2];
    const float* Wq  = (const float*)d_in[3];
    const float* bq  = (const float*)d_in[4];
    const float* Wk  = (const float*)d_in[5];
    const float* bk  = (const float*)d_in[6];
    const float* Wv  = (const float*)d_in[7];
    const float* bv  = (const float*)d_in[8];
    const float* Wo  = (const float*)d_in[9];
    const float* bo  = (const float*)d_in[10];

    const size_t TENS = (size_t)TOKENS * EMB;    // 4,194,304 elems
    const size_t WEL  = (size_t)EMB * EMB;       // 1,048,576 elems
    __bf16* ws = (__bf16*)d_ws;
    __bf16* Xin  = ws;                           // [3][4096][1024]
    __bf16* Wb   = ws + 3 * TENS;                // [4][1024][1024]
    __bf16* QKVp = ws + 3 * TENS + 4 * WEL;      // [4096][3072] (V cols hold V^T map)
    __bf16* Ap   = ws;                           // reuses Xin slab 0 (attn out)

    cvt4_kernel<<<dim3((unsigned)(TENS / 2048), 3), 256, 0, stream>>>(
        Qin, Kin, Vin, Vin, Xin, (int)TENS);
    cvt4_kernel<<<dim3((unsigned)(WEL / 2048), 4), 256, 0, stream>>>(
        Wq, Wk, Wv, Wo, Wb, (int)WEL);

    // merged QKV projection (V^T fused into epilogue): grid (24,32)=768
    gemm_qkv<<<dim3(QSTR / 128, TOKENS / 128), 256, 0, stream>>>(
        Xin, Wb, bq, bk, bv, QKVp);

    // 1-D grid, de-twinned XCD-local mapping (see attn_kernel comment)
    attn_kernel<<<dim3(16 * 32), 256, 0, stream>>>(QKVp, Ap);

    // output projection: 128x64 tiles, grid (16,32)=512
    gemm_fast<float><<<dim3(EMB / 64, TOKENS / 128), 256, 0, stream>>>(
        Ap, Wb + 3 * WEL, bo, (float*)d_out, EMB);
}

// Round 13
// 219.173 us; speedup vs baseline: 1.0970x; 1.0298x over previous
//
#include <hip/hip_runtime.h>
#include <hip/hip_bf16.h>

typedef __bf16  bf16x8 __attribute__((ext_vector_type(8)));
typedef float   f32x4  __attribute__((ext_vector_type(4)));
typedef float   f32x16 __attribute__((ext_vector_type(16)));

#define EMB   1024
#define QSTR  3072                  // packed QKV row stride
#define HD    64
#define NH    16
#define SEQ   2048
#define BATCH 2
#define TOKENS (BATCH*SEQ)
#define TK    64                    // attention K-tile per group per barrier

// native 2^x (v_exp_f32). Host pass sees fallback; device pass gets builtin.
#if __has_builtin(__builtin_amdgcn_exp2f)
#define EXP2(x) __builtin_amdgcn_exp2f(x)
#else
#define EXP2(x) __expf((x) * 0.69314718f)
#endif

// ---------------------------------------------------------------------------
// async global->LDS, 16 B per lane. LDS dest = wave-uniform base + lane*16.
// ---------------------------------------------------------------------------
typedef __attribute__((address_space(1))) unsigned int* gp_t;
typedef __attribute__((address_space(3))) unsigned int* lp_t;
__device__ __forceinline__ void gload16(const __bf16* g, __bf16* l) {
    __builtin_amdgcn_global_load_lds((gp_t)(unsigned long long)(const void*)g,
                                     (lp_t)(unsigned int)(unsigned long long)(void*)l,
                                     16, 0, 0);
}

// pack two f32 -> one u32 of 2 bf16
__device__ __forceinline__ unsigned int pack2(float a, float b) {
    unsigned short u0 = __builtin_bit_cast(unsigned short, (__bf16)a);
    unsigned short u1 = __builtin_bit_cast(unsigned short, (__bf16)b);
    return (unsigned int)u0 | ((unsigned int)u1 << 16);
}

// ---------------------------------------------------------------------------
// fp32 -> bf16, up to 4 sources selected by blockIdx.y, contiguous dst slabs.
// ---------------------------------------------------------------------------
__global__ __launch_bounds__(256) void cvt4_kernel(
    const float* __restrict__ s0, const float* __restrict__ s1,
    const float* __restrict__ s2, const float* __restrict__ s3,
    __bf16* __restrict__ dst, int n_per)
{
    const float* s = (blockIdx.y == 0) ? s0 : (blockIdx.y == 1) ? s1
                   : (blockIdx.y == 2) ? s2 : s3;
    int i = (blockIdx.x * 256 + threadIdx.x) * 8;
    if (i >= n_per) return;
    float4 a = *(const float4*)(s + i);
    float4 b = *(const float4*)(s + i + 4);
    __bf16 o[8] = {(__bf16)a.x, (__bf16)a.y, (__bf16)a.z, (__bf16)a.w,
                   (__bf16)b.x, (__bf16)b.y, (__bf16)b.z, (__bf16)b.w};
    *(uint4*)(dst + (size_t)blockIdx.y * n_per + i) = *(const uint4*)o;
}

// ---------------------------------------------------------------------------
// QKV GEMM: tile 128(M) x 128(N), BK=32, dbuf + global_load_lds prefetch.
// V-slab blocks (bn>=16) transpose their output tile in LDS and write
// V^T into the dead V-column region of QKVp:
//   vt_addr(bh,d,tok) = ((bh*64+d)*2 + (tok>>10))*QSTR + 2048 + (tok&1023)
// ---------------------------------------------------------------------------
__global__ __launch_bounds__(256, 3) void gemm_qkv(
    const __bf16* __restrict__ X, const __bf16* __restrict__ Wt,
    const float* __restrict__ b0, const float* __restrict__ b1,
    const float* __restrict__ b2, __bf16* __restrict__ Y)
{
    __shared__ __align__(16) __bf16 SMEM[4 * 128 * 32];   // 32 KB total
    // A dbuf at 0 / 4096; B dbuf at 8192 / 12288; epilogue T buf at 0 (18 KB)

    const int tid  = threadIdx.x;
    const int wave = tid >> 6;
    const int lane = tid & 63;
    const int quad = lane >> 4;
    const int l16  = lane & 15;
    const int warp_m = wave >> 1;
    const int warp_n = wave & 1;

    const int bm = blockIdx.y;
    const int bn = blockIdx.x;

    const int lr = lane >> 2;
    const int lc = (lane & 3) ^ ((lr >> 1) & 3);
    const __bf16* Ag = X + (size_t)(bn >> 3) * TOKENS * EMB
                         + (size_t)(bm * 128 + wave * 32 + lr) * EMB + lc * 8;
    const __bf16* Bg = Wt + (size_t)(bn * 128 + wave * 32 + lr) * EMB + lc * 8;
    const int off = wave * 1024;

    f32x4 acc[4][4] = {};

    gload16(Ag,            SMEM + off);
    gload16(Ag + 16 * EMB, SMEM + off + 512);
    gload16(Bg,            SMEM + 8192 + off);
    gload16(Bg + 16 * EMB, SMEM + 8192 + off + 512);

    for (int t = 0; t < EMB / 32; ++t) {
        const int cur = t & 1, nxt = cur ^ 1;
        __syncthreads();
        if (t + 1 < EMB / 32) {
            const __bf16* a0 = Ag + (t + 1) * 32;
            const __bf16* w0 = Bg + (t + 1) * 32;
            gload16(a0,            SMEM + nxt * 4096 + off);
            gload16(a0 + 16 * EMB, SMEM + nxt * 4096 + off + 512);
            gload16(w0,            SMEM + 8192 + nxt * 4096 + off);
            gload16(w0 + 16 * EMB, SMEM + 8192 + nxt * 4096 + off + 512);
        }

        const __bf16* Acur = SMEM + cur * 4096;
        const __bf16* Bcur = SMEM + 8192 + cur * 4096;
        bf16x8 af[4], bf[4];
        #pragma unroll
        for (int i = 0; i < 4; ++i) {
            int rowa = warp_m * 64 + i * 16 + l16;
            int rowb = warp_n * 64 + i * 16 + l16;
            af[i] = *(const bf16x8*)(Acur + (rowa * 4 + (quad ^ ((rowa >> 1) & 3))) * 8);
            bf[i] = *(const bf16x8*)(Bcur + (rowb * 4 + (quad ^ ((rowb >> 1) & 3))) * 8);
        }
        #pragma unroll
        for (int i = 0; i < 4; ++i)
            #pragma unroll
            for (int j = 0; j < 4; ++j)
                acc[i][j] = __builtin_amdgcn_mfma_f32_16x16x32_bf16(af[i], bf[j], acc[i][j], 0, 0, 0);
    }

    if (bn < 16) {
        // Q / K slabs: normal row-major write
        #pragma unroll
        for (int i = 0; i < 4; ++i)
            #pragma unroll
            for (int j = 0; j < 4; ++j) {
                int n = bn * 128 + warp_n * 64 + j * 16 + l16;
                const float* bsel = (n < 1024) ? b0 : b1;
                float bj = bsel[n & 1023];
                #pragma unroll
                for (int r = 0; r < 4; ++r) {
                    int m = bm * 128 + warp_m * 64 + i * 16 + quad * 4 + r;
                    Y[(size_t)m * QSTR + n] = (__bf16)(acc[i][j][r] + bj);
                }
            }
    } else {
        // V slab: bias + transpose (two 64-token halves through T) -> V^T map
        __bf16* T = SMEM;                     // [128][72] transpose buffer
        const int b_   = bm >> 4;
        const int tokl = (bm & 15) * 128;
        #pragma unroll
        for (int half = 0; half < 2; ++half) {
            __syncthreads();
            if (warp_m == half) {
                #pragma unroll
                for (int i = 0; i < 4; ++i)
                    #pragma unroll
                    for (int j = 0; j < 4; ++j) {
                        int nl = warp_n * 64 + j * 16 + l16;
                        float bj = b2[(bn & 7) * 128 + nl];
                        #pragma unroll
                        for (int r = 0; r < 4; ++r) {
                            int ml = i * 16 + quad * 4 + r;     // token-local 0..63
                            T[nl * 72 + ml] = (__bf16)(acc[i][j][r] + bj);
                        }
                    }
            }
            __syncthreads();
            {
                const int nl  = tid >> 1;                 // V column-local 0..127
                const int seg = tid & 1;
                const int hh  = (bn - 16) * 2 + (nl >> 6);
                const int dd  = nl & 63;
                const int tok0 = tokl + half * 64 + seg * 32;
                const int bh_ = b_ * NH + hh;
                __bf16* dst = Y + ((size_t)((bh_ * 64 + dd) * 2 + (tok0 >> 10))) * QSTR
                                + 2048 + (tok0 & 1023);
                #pragma unroll
                for (int k = 0; k < 4; ++k)
                    *(uint4*)(dst + k * 8) = *(const uint4*)&T[nl * 72 + seg * 32 + k * 8];
            }
        }
    }
}

// ---------------------------------------------------------------------------
// Final GEMM (R10-proven): tile 128x64, BK=64, dbuf + gload prefetch.
// ---------------------------------------------------------------------------
template <typename TY>
__global__ __launch_bounds__(256) void gemm_fast(
    const __bf16* __restrict__ X, const __bf16* __restrict__ Wt,
    const float* __restrict__ b0, TY* __restrict__ Y, int ldy)
{
    __shared__ __align__(16) __bf16 As[2][128 * 64];
    __shared__ __align__(16) __bf16 Bs[2][64 * 64];

    const int tid  = threadIdx.x;
    const int wave = tid >> 6;
    const int lane = tid & 63;
    const int quad = lane >> 4;
    const int l16  = lane & 15;
    const int warp_m = wave >> 1;
    const int warp_n = wave & 1;

    const int bm = blockIdx.y;
    const int bn = blockIdx.x;

    const int lr = lane >> 3;
    const int lc = (lane & 7) ^ lr;
    const __bf16* Ag = X + (size_t)(bm * 128 + wave * 32 + lr) * EMB + lc * 8;
    const __bf16* Bg = Wt + (size_t)(bn * 64 + wave * 16 + lr) * EMB + lc * 8;
    const int aoff = wave * 2048;
    const int boff = wave * 1024;

    f32x4 acc[4][2] = {};

    gload16(Ag,            As[0] + aoff);
    gload16(Ag +  8 * EMB, As[0] + aoff + 512);
    gload16(Ag + 16 * EMB, As[0] + aoff + 1024);
    gload16(Ag + 24 * EMB, As[0] + aoff + 1536);
    gload16(Bg,            Bs[0] + boff);
    gload16(Bg +  8 * EMB, Bs[0] + boff + 512);

    for (int t = 0; t < EMB / 64; ++t) {
        const int cur = t & 1, nxt = cur ^ 1;
        __syncthreads();
        if (t + 1 < EMB / 64) {
            const __bf16* a0 = Ag + (t + 1) * 64;
            const __bf16* w0 = Bg + (t + 1) * 64;
            gload16(a0,            As[nxt] + aoff);
            gload16(a0 +  8 * EMB, As[nxt] + aoff + 512);
            gload16(a0 + 16 * EMB, As[nxt] + aoff + 1024);
            gload16(a0 + 24 * EMB, As[nxt] + aoff + 1536);
            gload16(w0,            Bs[nxt] + boff);
            gload16(w0 +  8 * EMB, Bs[nxt] + boff + 512);
        }

        #pragma unroll
        for (int kk = 0; kk < 2; ++kk) {
            bf16x8 af[4], bf[2];
            #pragma unroll
            for (int i = 0; i < 4; ++i) {
                int row = warp_m * 64 + i * 16 + l16;
                af[i] = *(const bf16x8*)(As[cur] + (row * 8 + ((kk * 4 + quad) ^ (row & 7))) * 8);
            }
            #pragma unroll
            for (int j = 0; j < 2; ++j) {
                int row = warp_n * 32 + j * 16 + l16;
                bf[j] = *(const bf16x8*)(Bs[cur] + (row * 8 + ((kk * 4 + quad) ^ (row & 7))) * 8);
            }
            #pragma unroll
            for (int i = 0; i < 4; ++i)
                #pragma unroll
                for (int j = 0; j < 2; ++j)
                    acc[i][j] = __builtin_amdgcn_mfma_f32_16x16x32_bf16(af[i], bf[j], acc[i][j], 0, 0, 0);
        }
    }

    #pragma unroll
    for (int i = 0; i < 4; ++i)
        #pragma unroll
        for (int j = 0; j < 2; ++j) {
            int n = bn * 64 + warp_n * 32 + j * 16 + l16;
            float bj = b0[n];
            #pragma unroll
            for (int r = 0; r < 4; ++r) {
                int m = bm * 128 + warp_m * 64 + i * 16 + quad * 4 + r;
                Y[(size_t)m * ldy + n] = (TY)(acc[i][j][r] + bj);
            }
        }
}

// ---------------------------------------------------------------------------
// Flash attention, in-block k-split for 2x occupancy (R12 -> R13).
// 512 threads = 8 waves = 2 groups x 4 waves. Group g handles k-half
// [g*1024, g*1024+1024) for the SAME 128 q rows; each group has its own
// TK=64 double-buffered K/V LDS (16 KB/group/buf-pair = 64 KB block total
// -> 2 blocks/CU -> 16 waves/CU = 4/SIMD, double R12's TLP).
// Fixed-max softmax => partials combine LINEARLY: group1 writes O/l
// partials to LDS after the loop; group0 adds, divides, stores.
// Keeps R12's wins: XCD-local de-twinned grid (FETCH 70->12 MB),
// native v_exp_f32 on log2-domain scores, swizzled gload_lds staging.
// ---------------------------------------------------------------------------
__global__ __launch_bounds__(512, 4) void attn_kernel(
    const __bf16* __restrict__ QKV, __bf16* __restrict__ Op)
{
    // per-group layout (elems): +0 K dbuf [2][4096], +8192 V dbuf [2][4096]
    __shared__ __align__(16) __bf16 SM[2 * 16384];     // 64 KB

    const int tid  = threadIdx.x;        // 0..511
    const int wave = tid >> 6;           // 0..7
    const int grp  = wave >> 2;          // k-half group
    const int w4   = wave & 3;           // q-subtile within group
    const int gtid = tid & 255;          // thread id within group
    const int lane = tid & 63;
    const int l31  = lane & 31;
    const int hi   = lane >> 5;
    const int e7   = l31 & 7;

    // de-twinned XCD-local mapping (R12-proven)
    const int bid = blockIdx.x;
    const int qt  = bid >> 5;
    const int bh  = ((bid & 31) - (qt & 8)) & 31;   // = b*NH + h
    const int b   = bh >> 4;
    const int h   = bh & 15;

    const size_t qoff  = (size_t)b * SEQ * QSTR + (size_t)h * HD;
    const size_t obase = (size_t)b * SEQ * EMB  + (size_t)h * HD;
    const int qbase = qt * 128 + w4 * 32;

    __bf16* KsG = SM + grp * 16384;          // K dbuf: +cur*4096
    __bf16* VsG = SM + grp * 16384 + 8192;   // V dbuf: +cur*4096

    // Q fragments: lane holds Q[q=l31][d = dc*16 + 8*hi + j],
    // scaled by 0.125 * log2(e) so QK^T yields log2-domain scores.
    const float qscale = 0.125f * 1.44269504f;
    bf16x8 aq[4];
    {
        const __bf16* qrow = QKV + qoff + (size_t)(qbase + l31) * QSTR + hi * 8;
        #pragma unroll
        for (int dc = 0; dc < 4; ++dc) {
            bf16x8 v = *(const bf16x8*)(qrow + dc * 16);
            #pragma unroll
            for (int i = 0; i < 8; ++i) v[i] = (__bf16)((float)v[i] * qscale);
            aq[dc] = v;
        }
    }

    float  l4[4] = {};
    f32x16 oacc[2] = {};

    // ---- staging geometry (pre-swizzled source, linear LDS dest) ----
    // K: group's 256 threads cover rows kr, kr+32 of the 64-row tile
    const int kr = gtid >> 3;
    const int kc = ((gtid & 7) ^ (kr & 7)) << 3;
    const __bf16* Kg0 = QKV + qoff + EMB + (size_t)kr * QSTR + kc;
    // V^T: d-rows vr, vr+32; source from QKVp dead-space map
    const int vr  = gtid >> 3;
    const int vcl = ((gtid & 7) ^ (vr & 7)) << 3;
    const __bf16* Vg0 = QKV + ((size_t)(bh * 64 + vr) * 2) * QSTR + 2048 + vcl;

    #define STAGE(buf, kb)                                                        \
        {                                                                         \
            gload16(Kg0 + (size_t)(kb) * QSTR,        KsG + (buf) * 4096 + gtid * 8);        \
            gload16(Kg0 + (size_t)((kb) + 32) * QSTR, KsG + (buf) * 4096 + 2048 + gtid * 8); \
            const size_t vt_ = (size_t)((kb) >> 10) * QSTR + ((kb) & 1023);       \
            gload16(Vg0 + vt_,             VsG + (buf) * 4096 + gtid * 8);        \
            gload16(Vg0 + 64 * QSTR + vt_, VsG + (buf) * 4096 + 2048 + gtid * 8); \
        }

    const int kofs = grp * 1024;         // group's k-half base
    STAGE(0, kofs);

    for (int t = 0; t < 16; ++t) {
        const int cur = t & 1, nxt = cur ^ 1;
        __syncthreads();                 // vmcnt drained -> buf[cur] ready
        if (t + 1 < 16) STAGE(nxt, kofs + (t + 1) * TK);

        const __bf16* Kc = KsG + cur * 4096;
        const __bf16* Vc = VsG + cur * 4096;

        // ---- S^T = K Q^T (log2 domain) ----
        f32x16 s[2] = {};
        #pragma unroll
        for (int kt = 0; kt < 2; ++kt)
            #pragma unroll
            for (int dc = 0; dc < 4; ++dc) {
                bf16x8 kf = *(const bf16x8*)(Kc + (kt * 32 + l31) * 64
                                             + (((2 * dc + hi) ^ e7) << 3));
                s[kt] = __builtin_amdgcn_mfma_f32_32x32x16_bf16(kf, aq[dc], s[kt], 0, 0, 0);
            }

        // ---- exp2 + pack ----
        unsigned int pw[2][4][2];
        #pragma unroll
        for (int kt = 0; kt < 2; ++kt)
            #pragma unroll
            for (int bq = 0; bq < 4; ++bq) {
                float e0 = EXP2(s[kt][bq * 4 + 0]);
                float e1 = EXP2(s[kt][bq * 4 + 1]);
                float e2 = EXP2(s[kt][bq * 4 + 2]);
                float e3 = EXP2(s[kt][bq * 4 + 3]);
                l4[(kt * 4 + bq) & 3] += (e0 + e1) + (e2 + e3);
                pw[kt][bq][0] = pack2(e0, e1);
                pw[kt][bq][1] = pack2(e2, e3);
            }

        // ---- hi-half word exchange -> PV A-frags (k = ks*16+8*hi+jj) ----
        bf16x8 paf[4];
        #pragma unroll
        for (int kt = 0; kt < 2; ++kt)
            #pragma unroll
            for (int m = 0; m < 2; ++m) {
                unsigned x0 = pw[kt][2 * m][0],     x1 = pw[kt][2 * m][1];
                unsigned y0 = pw[kt][2 * m + 1][0], y1 = pw[kt][2 * m + 1][1];
                unsigned px0 = __shfl_xor(x0, 32, 64), px1 = __shfl_xor(x1, 32, 64);
                unsigned py0 = __shfl_xor(y0, 32, 64), py1 = __shfl_xor(y1, 32, 64);
                uint4 fw;
                fw.x = hi ? py0 : x0;
                fw.y = hi ? py1 : x1;
                fw.z = hi ? y0  : px0;
                fw.w = hi ? y1  : px1;
                paf[kt * 2 + m] = __builtin_bit_cast(bf16x8, fw);
            }

        // ---- O += P V (32x32x16) ----
        #pragma unroll
        for (int dh = 0; dh < 2; ++dh)
            #pragma unroll
            for (int ks = 0; ks < 4; ++ks) {
                bf16x8 bvf = *(const bf16x8*)(Vc + (dh * 32 + l31) * 64
                                              + (((2 * ks + hi) ^ e7) << 3));
                oacc[dh] = __builtin_amdgcn_mfma_f32_32x32x16_bf16(paf[ks], bvf, oacc[dh], 0, 0, 0);
            }
    }

    // per-group denominator: lanes l and l+32 hold complementary k-columns
    float l_run = (l4[0] + l4[1]) + (l4[2] + l4[3]);
    float lf = l_run + __shfl_xor(l_run, 32, 64);

    // ---- cross-group combine through LDS (linear: fixed-max softmax) ----
    // F layout (floats): [0 .. 8191]  O partial  [w4][qr 0..31][d 0..63]
    //                    [8192..8319] l partial  [w4][q 0..31]
    float* F = (float*)SM;
    __syncthreads();                     // all K/V reads done; LDS reusable
    if (grp == 1) {
        #pragma unroll
        for (int r = 0; r < 16; ++r) {
            int qr = (r & 3) + 8 * (r >> 2) + 4 * hi;
            #pragma unroll
            for (int dh = 0; dh < 2; ++dh)
                F[w4 * 2048 + qr * 64 + dh * 32 + l31] = oacc[dh][r];
        }
        if (lane < 32) F[8192 + w4 * 32 + l31] = lf;
    }
    __syncthreads();
    if (grp == 0) {
        float lt = lf + F[8192 + w4 * 32 + l31];
        #pragma unroll
        for (int r = 0; r < 16; ++r) {
            int qr = (r & 3) + 8 * (r >> 2) + 4 * hi;
            float lq = __shfl(lt, qr, 64);           // lane qr (0..31) holds l[qr]
            #pragma unroll
            for (int dh = 0; dh < 2; ++dh) {
                float o = oacc[dh][r] + F[w4 * 2048 + qr * 64 + dh * 32 + l31];
                Op[obase + (size_t)(qbase + qr) * EMB + dh * 32 + l31] = (__bf16)(o / lq);
            }
        }
    }
    #undef STAGE
}

// ---------------------------------------------------------------------------
extern "C" void kernel_launch(void* const* d_in, const int* in_sizes, int n_in,
                              void* d_out, int out_size, void* d_ws, size_t ws_size,
                              hipStream_t stream) {
    const float* Qin = (const float*)d_in[0];
    const float* Kin = (const float*)d_in[1];
    const float* Vin = (const float*)d_in[2];
    const float* Wq  = (const float*)d_in[3];
    const float* bq  = (const float*)d_in[4];
    const float* Wk  = (const float*)d_in[5];
    const float* bk  = (const float*)d_in[6];
    const float* Wv  = (const float*)d_in[7];
    const float* bv  = (const float*)d_in[8];
    const float* Wo  = (const float*)d_in[9];
    const float* bo  = (const float*)d_in[10];

    const size_t TENS = (size_t)TOKENS * EMB;    // 4,194,304 elems
    const size_t WEL  = (size_t)EMB * EMB;       // 1,048,576 elems
    __bf16* ws = (__bf16*)d_ws;
    __bf16* Xin  = ws;                           // [3][4096][1024]
    __bf16* Wb   = ws + 3 * TENS;                // [4][1024][1024]
    __bf16* QKVp = ws + 3 * TENS + 4 * WEL;      // [4096][3072] (V cols hold V^T map)
    __bf16* Ap   = ws;                           // reuses Xin slab 0 (attn out)

    cvt4_kernel<<<dim3((unsigned)(TENS / 2048), 3), 256, 0, stream>>>(
        Qin, Kin, Vin, Vin, Xin, (int)TENS);
    cvt4_kernel<<<dim3((unsigned)(WEL / 2048), 4), 256, 0, stream>>>(
        Wq, Wk, Wv, Wo, Wb, (int)WEL);

    // merged QKV projection (V^T fused into epilogue): grid (24,32)=768
    gemm_qkv<<<dim3(QSTR / 128, TOKENS / 128), 256, 0, stream>>>(
        Xin, Wb, bq, bk, bv, QKVp);

    // 1-D grid, de-twinned XCD-local mapping; 512 threads (2 k-split groups)
    attn_kernel<<<dim3(16 * 32), 512, 0, stream>>>(QKVp, Ap);

    // output projection: 128x64 tiles, grid (16,32)=512
    gemm_fast<float><<<dim3(EMB / 64, TOKENS / 128), 256, 0, stream>>>(
        Ap, Wb + 3 * WEL, bo, (float*)d_out, EMB);
}